// Round 1
// 197.884 us; speedup vs baseline: 1.0158x; 1.0158x over previous
//
#include <hip/hip_runtime.h>
#include <cstdint>
#include <cstddef>

typedef unsigned short u16;
typedef __bf16 bf16x8 __attribute__((ext_vector_type(8)));
typedef float floatx4 __attribute__((ext_vector_type(4)));

#define NPTS 4096
#define MGRD 4096
#define DDIM 8

// round-to-nearest-even fp32 -> bf16
static __device__ __forceinline__ u16 f2bf(float f) {
    uint32_t u = __float_as_uint(f);
    u += 0x7fffu + ((u >> 16) & 1u);
    return (u16)(u >> 16);
}

// ---------------- Fused prep (unchanged from R4/R5 version) ----------------
__global__ __launch_bounds__(256) void prep_kernel(
    const float* __restrict__ x, const float* __restrict__ g,
    const float* __restrict__ ls, const float* __restrict__ B,
    u16* __restrict__ A, u16* __restrict__ Bt)
{
    __shared__ float tile[64][65];
    const int bid = blockIdx.x;
    const int tid = threadIdx.x;

    if (bid < 512) {
        // ---- kstar ----
        const int kb = bid & 1;
        const int n0 = (bid >> 1) * 16;
        const int k0 = kb * 2048 + tid * 8;

        float il[DDIM];
#pragma unroll
        for (int d = 0; d < DDIM; ++d) il[d] = 1.0f / ls[d];

        float4 g0[8], g1[8];
#pragma unroll
        for (int r = 0; r < 8; ++r) {
            g0[r] = *reinterpret_cast<const float4*>(g + (size_t)(k0 + r) * DDIM);
            g1[r] = *reinterpret_cast<const float4*>(g + (size_t)(k0 + r) * DDIM + 4);
        }

        for (int nn = 0; nn < 16; ++nn) {
            const int n = n0 + nn;
            const float4 x0 = *reinterpret_cast<const float4*>(x + (size_t)n * DDIM);
            const float4 x1 = *reinterpret_cast<const float4*>(x + (size_t)n * DDIM + 4);
            alignas(16) u16 res[8];
#pragma unroll
            for (int r = 0; r < 8; ++r) {
                float s = fabsf(x0.x - g0[r].x) * il[0] + fabsf(x0.y - g0[r].y) * il[1]
                        + fabsf(x0.z - g0[r].z) * il[2] + fabsf(x0.w - g0[r].w) * il[3]
                        + fabsf(x1.x - g1[r].x) * il[4] + fabsf(x1.y - g1[r].y) * il[5]
                        + fabsf(x1.z - g1[r].z) * il[6] + fabsf(x1.w - g1[r].w) * il[7];
                res[r] = f2bf(__expf(-s));
            }
            *reinterpret_cast<uint4*>(A + (size_t)n * MGRD + k0) =
                *reinterpret_cast<const uint4*>(res);
        }
    } else {
        // ---- transpose + convert (block-lower-triangular tiles only) ----
        const int id = bid - 512;
        const int bx = id & 63;
        const int by = id >> 6;
        if (by < (bx & ~1)) return;
        const int k0 = by * 64;
        const int m0 = bx * 64;

#pragma unroll
        for (int r = 0; r < 4; ++r) {
            int c   = r * 256 + tid;
            int row = c >> 4;
            int col = (c & 15) * 4;
            const float4 v = *reinterpret_cast<const float4*>(&B[(size_t)(k0 + row) * MGRD + m0 + col]);
            tile[row][col + 0] = v.x; tile[row][col + 1] = v.y;
            tile[row][col + 2] = v.z; tile[row][col + 3] = v.w;
        }
        __syncthreads();

#pragma unroll
        for (int r = 0; r < 2; ++r) {
            int c  = r * 256 + tid;
            int mr = c >> 3;
            int kc = (c & 7) * 8;
            alignas(16) u16 tmp[8];
#pragma unroll
            for (int j = 0; j < 8; ++j)
                tmp[j] = f2bf(tile[kc + j][mr]);
            *reinterpret_cast<uint4*>(&Bt[(size_t)(m0 + mr) * MGRD + k0 + kc]) =
                *reinterpret_cast<const uint4*>(tmp);
        }
    }
}

// ---------------- R6: 8-phase counted-vmcnt triangular GEMM ----------------
// Tile 256n x 128m, BK=64, 512 thr / 8 waves (4n x 2m), per-wave 64x64 out.
// 512 blocks, longest-first (bm = id>>4): dynamic pack -> ~66-68 K-steps/CU
// vs 66 ideal; no split-K needed.
// Single rolling LDS buffer (48 KB): all 16 frags/K-tile go to registers, so
// each half is LDS-read in exactly one phase and restaged one phase after its
// last read (A-h0,B-h0 @P2; B-h1 @P3; A-h1 @P4) => uniform 3-phase load
// flight. Derived per-wave vmcnt ledger (in-flight 3..6, never 0 in loop):
//   P1-end vmcnt(2)  confirms B-h1(T)   [keeps A-h1(T) x2]
//   P2-end vmcnt(3)  confirms A-h1(T)   [keeps P2's 3 issues]
//   P3-end --        (P4 reads nothing)
//   P4-end vmcnt(3)  confirms A-h0,B-h0(T+1) [keeps B-h1,A-h1(T+1)]
// LDS layout: halves hold rows with (row&63)<32 / >=32 so that one
// global_load_lds inst (512 lanes x 16B = 64 rows) stays within one half.
// XOR k-chunk swizzle identical to R2-verified pattern (key = rowInHalf&7 ==
// lrow&7 on the read side; conflict-counter was 0).

#define FENCE() asm volatile("" ::: "memory")
static __device__ __forceinline__ void bar() {
    FENCE(); __builtin_amdgcn_s_barrier(); FENCE();
}

__global__ __launch_bounds__(512, 2) void gemm8_kernel(
    const u16* __restrict__ A,    // [4096][4096] bf16 (n-major, k contiguous)
    const u16* __restrict__ Bt,   // [4096][4096] bf16 (m-major, k contiguous)
    float* __restrict__ C)        // [4096][4096] fp32
{
    __shared__ u16 sA[2][128 * 64] __attribute__((aligned(16)));  // [half][row][k] 32 KB
    __shared__ u16 sB[2][64 * 64]  __attribute__((aligned(16)));  // [half][row][k] 16 KB

    const int tid  = threadIdx.x;
    const int lane = tid & 63;
    const int w    = tid >> 6;          // 0..7
    const int wn   = (w >> 1) * 64;     // wave n-offset in 256-row tile
    const int wmm  = (w & 1) * 64;      // wave m-offset in 128-col tile
    const int lrow = lane & 15;
    const int lhi  = lane >> 4;
    const int r7   = lrow & 7;

    const int id  = blockIdx.x;
    const int bm  = id >> 4;            // 0..31, longest (bm=0) dispatched first
    const int bn  = id & 15;
    const int bn0 = bn << 8;
    const int bm0 = bm << 7;
    const int L   = 64 - 2 * bm;        // K-tiles (always even, >= 2)

    // per-thread global source offsets (elements); k0 added at issue time.
    // A inst (h, r): chunk c = r*512+tid; rowInHalf = c>>3; swizzled k-chunk.
    int aoff[2][2], boff[2];
#pragma unroll
    for (int h = 0; h < 2; ++h)
#pragma unroll
        for (int r = 0; r < 2; ++r) {
            int c    = r * 512 + tid;
            int rowh = c >> 3;                       // 0..127
            int kc   = ((c ^ rowh) & 7) * 8;
            int grow = bn0 + (rowh >> 5) * 64 + h * 32 + (rowh & 31);
            aoff[h][r] = grow * 4096 + kc;
        }
#pragma unroll
    for (int h = 0; h < 2; ++h) {
        int rowh = tid >> 3;                         // 0..63
        int kc   = ((tid ^ rowh) & 7) * 8;
        int growm = bm0 + (rowh >> 5) * 64 + h * 32 + (rowh & 31);
        boff[h] = growm * 4096 + kc;
    }

#define STAGE_A(h, r, k)                                                        \
    __builtin_amdgcn_global_load_lds(                                           \
        (const __attribute__((address_space(1))) void*)(A + (size_t)aoff[h][r] + (k)), \
        (__attribute__((address_space(3))) void*)(&sA[h][((r) * 512 + w * 64) * 8]),   \
        16, 0, 0)
#define STAGE_B(h, k)                                                           \
    __builtin_amdgcn_global_load_lds(                                           \
        (const __attribute__((address_space(1))) void*)(Bt + (size_t)boff[h] + (k)),   \
        (__attribute__((address_space(3))) void*)(&sB[h][(w * 64) * 8]),        \
        16, 0, 0)

    const int aidx0 = wn >> 1;    // half-local row base for af
    const int bidx0 = wmm >> 1;   // half-local row base for bf

#define RD_A(i, s) (*reinterpret_cast<const bf16x8*>(                           \
    &sA[(i) >> 1][(size_t)(aidx0 + ((i) & 1) * 16 + lrow) * 64 + ((((s) * 4 + lhi) ^ r7) * 8)]))
#define RD_B(j, s) (*reinterpret_cast<const bf16x8*>(                           \
    &sB[(j) >> 1][(size_t)(bidx0 + ((j) & 1) * 16 + lrow) * 64 + ((((s) * 4 + lhi) ^ r7) * 8)]))

    floatx4 acc[4][4];
#pragma unroll
    for (int i = 0; i < 4; ++i)
#pragma unroll
        for (int j = 0; j < 4; ++j)
            acc[i][j] = (floatx4)0.0f;

    bf16x8 af[4][2], bfr[4][2];

#define READ_AF01() do { af[0][0]=RD_A(0,0); af[0][1]=RD_A(0,1);                \
                         af[1][0]=RD_A(1,0); af[1][1]=RD_A(1,1); } while (0)
#define READ_AF23() do { af[2][0]=RD_A(2,0); af[2][1]=RD_A(2,1);                \
                         af[3][0]=RD_A(3,0); af[3][1]=RD_A(3,1); } while (0)
#define READ_BF01() do { bfr[0][0]=RD_B(0,0); bfr[0][1]=RD_B(0,1);              \
                         bfr[1][0]=RD_B(1,0); bfr[1][1]=RD_B(1,1); } while (0)
#define READ_BF23() do { bfr[2][0]=RD_B(2,0); bfr[2][1]=RD_B(2,1);              \
                         bfr[3][0]=RD_B(3,0); bfr[3][1]=RD_B(3,1); } while (0)

#define MM(i, j, s) acc[i][j] = __builtin_amdgcn_mfma_f32_16x16x32_bf16(        \
    af[i][s], bfr[j][s], acc[i][j], 0, 0, 0)
#define MFMA_Q(qi, qj) do {                                                     \
    __builtin_amdgcn_s_setprio(1);                                              \
    MM(2*(qi)+0, 2*(qj)+0, 0); MM(2*(qi)+0, 2*(qj)+1, 0);                       \
    MM(2*(qi)+1, 2*(qj)+0, 0); MM(2*(qi)+1, 2*(qj)+1, 0);                       \
    MM(2*(qi)+0, 2*(qj)+0, 1); MM(2*(qi)+0, 2*(qj)+1, 1);                       \
    MM(2*(qi)+1, 2*(qj)+0, 1); MM(2*(qi)+1, 2*(qj)+1, 1);                       \
    __builtin_amdgcn_s_setprio(0);                                              \
} while (0)

    // ---- prologue: stage tile 0 (reverse-K: tile T at k = 4032 - 64T) ----
    int kT = 4096 - 64;
    STAGE_A(0, 0, kT); STAGE_A(0, 1, kT);   // A-h0  (2)
    STAGE_B(0, kT);                          // B-h0  (1)
    STAGE_B(1, kT);                          // B-h1  (1)
    STAGE_A(1, 0, kT); STAGE_A(1, 1, kT);   // A-h1  (2)
    asm volatile("s_waitcnt vmcnt(3)" ::: "memory");  // A-h0,B-h0 arrived
    bar();

    // ---- main loop: tiles 0..L-2, staging tile T+1 while computing T ----
    for (int T = 0; T < L - 1; ++T, kT -= 64) {
        const int kn = kT - 64;
        // P1: q(0,0) -- reads A-h0, B-h0
        READ_AF01(); READ_BF01();
        bar();
        MFMA_Q(0, 0);
        asm volatile("s_waitcnt vmcnt(2)" ::: "memory");  // B-h1(T) arrived
        bar();
        // P2: q(0,1) -- reads B-h1; restage A-h0,B-h0 (free since P1)
        READ_BF23();
        STAGE_A(0, 0, kn); STAGE_A(0, 1, kn); STAGE_B(0, kn);
        bar();
        MFMA_Q(0, 1);
        asm volatile("s_waitcnt vmcnt(3)" ::: "memory");  // A-h1(T) arrived
        bar();
        // P3: q(1,0) -- reads A-h1; restage B-h1 (free since P2)
        READ_AF23();
        STAGE_B(1, kn);
        bar();
        MFMA_Q(1, 0);
        bar();
        // P4: q(1,1) -- all frags in regs; restage A-h1 (free since P3)
        STAGE_A(1, 0, kn); STAGE_A(1, 1, kn);
        bar();
        MFMA_Q(1, 1);
        asm volatile("s_waitcnt vmcnt(3)" ::: "memory");  // A-h0,B-h0(T+1) arrived
        bar();
    }

    // ---- peeled last tile (no staging) ----
    READ_AF01(); READ_BF01();
    bar();
    MFMA_Q(0, 0);
    asm volatile("s_waitcnt vmcnt(2)" ::: "memory");      // B-h1 arrived
    bar();
    READ_BF23();
    MFMA_Q(0, 1);
    asm volatile("s_waitcnt vmcnt(0)" ::: "memory");      // A-h1 arrived
    bar();
    READ_AF23();
    MFMA_Q(1, 0);
    MFMA_Q(1, 1);

    // ---- epilogue: C/D layout col=lane&15 (m), row=(lane>>4)*4+reg [m89] ----
#pragma unroll
    for (int i = 0; i < 4; ++i) {
        int rown = bn0 + wn + i * 16 + lhi * 4;
#pragma unroll
        for (int j = 0; j < 4; ++j) {
            int colm = bm0 + wmm + j * 16 + lrow;
            float* cp = C + (size_t)rown * 4096 + colm;
#pragma unroll
            for (int rr = 0; rr < 4; ++rr)
                cp[(size_t)rr * 4096] = acc[i][j][rr];
        }
    }
}

extern "C" void kernel_launch(void* const* d_in, const int* in_sizes, int n_in,
                              void* d_out, int out_size, void* d_ws, size_t ws_size,
                              hipStream_t stream)
{
    const float* x    = (const float*)d_in[0];   // [4096,8]
    const float* grid = (const float*)d_in[1];   // [4096,8]
    const float* ci   = (const float*)d_in[2];   // [4096,4096]
    const float* ls   = (const float*)d_in[3];   // [8]
    float* out = (float*)d_out;                  // [4096,4096] fp32

    u16* wsA  = (u16*)d_ws;                            // k_star bf16, 33.5 MB
    u16* wsBt = (u16*)d_ws + (size_t)MGRD * MGRD;      // chol_inv^T bf16, 33.5 MB

    prep_kernel<<<dim3(512 + 64 * 64), 256, 0, stream>>>(x, grid, ls, ci, wsA, wsBt);
    gemm8_kernel<<<dim3(512), 512, 0, stream>>>(wsA, wsBt, out);
}

// Round 2
// 189.726 us; speedup vs baseline: 1.0594x; 1.0430x over previous
//
#include <hip/hip_runtime.h>
#include <cstdint>
#include <cstddef>

typedef unsigned short u16;
typedef __bf16 bf16x8 __attribute__((ext_vector_type(8)));
typedef float floatx4 __attribute__((ext_vector_type(4)));

#define NPTS 4096
#define MGRD 4096
#define DDIM 8

// round-to-nearest-even fp32 -> bf16
static __device__ __forceinline__ u16 f2bf(float f) {
    uint32_t u = __float_as_uint(f);
    u += 0x7fffu + ((u >> 16) & 1u);
    return (u16)(u >> 16);
}

// ---------------- Fused prep (unchanged, verified) ----------------
__global__ __launch_bounds__(256) void prep_kernel(
    const float* __restrict__ x, const float* __restrict__ g,
    const float* __restrict__ ls, const float* __restrict__ B,
    u16* __restrict__ A, u16* __restrict__ Bt)
{
    __shared__ float tile[64][65];
    const int bid = blockIdx.x;
    const int tid = threadIdx.x;

    if (bid < 512) {
        const int kb = bid & 1;
        const int n0 = (bid >> 1) * 16;
        const int k0 = kb * 2048 + tid * 8;

        float il[DDIM];
#pragma unroll
        for (int d = 0; d < DDIM; ++d) il[d] = 1.0f / ls[d];

        float4 g0[8], g1[8];
#pragma unroll
        for (int r = 0; r < 8; ++r) {
            g0[r] = *reinterpret_cast<const float4*>(g + (size_t)(k0 + r) * DDIM);
            g1[r] = *reinterpret_cast<const float4*>(g + (size_t)(k0 + r) * DDIM + 4);
        }

        for (int nn = 0; nn < 16; ++nn) {
            const int n = n0 + nn;
            const float4 x0 = *reinterpret_cast<const float4*>(x + (size_t)n * DDIM);
            const float4 x1 = *reinterpret_cast<const float4*>(x + (size_t)n * DDIM + 4);
            alignas(16) u16 res[8];
#pragma unroll
            for (int r = 0; r < 8; ++r) {
                float s = fabsf(x0.x - g0[r].x) * il[0] + fabsf(x0.y - g0[r].y) * il[1]
                        + fabsf(x0.z - g0[r].z) * il[2] + fabsf(x0.w - g0[r].w) * il[3]
                        + fabsf(x1.x - g1[r].x) * il[4] + fabsf(x1.y - g1[r].y) * il[5]
                        + fabsf(x1.z - g1[r].z) * il[6] + fabsf(x1.w - g1[r].w) * il[7];
                res[r] = f2bf(__expf(-s));
            }
            *reinterpret_cast<uint4*>(A + (size_t)n * MGRD + k0) =
                *reinterpret_cast<const uint4*>(res);
        }
    } else {
        const int id = bid - 512;
        const int bx = id & 63;
        const int by = id >> 6;
        if (by < (bx & ~1)) return;
        const int k0 = by * 64;
        const int m0 = bx * 64;

#pragma unroll
        for (int r = 0; r < 4; ++r) {
            int c   = r * 256 + tid;
            int row = c >> 4;
            int col = (c & 15) * 4;
            const float4 v = *reinterpret_cast<const float4*>(&B[(size_t)(k0 + row) * MGRD + m0 + col]);
            tile[row][col + 0] = v.x; tile[row][col + 1] = v.y;
            tile[row][col + 2] = v.z; tile[row][col + 3] = v.w;
        }
        __syncthreads();

#pragma unroll
        for (int r = 0; r < 2; ++r) {
            int c  = r * 256 + tid;
            int mr = c >> 3;
            int kc = (c & 7) * 8;
            alignas(16) u16 tmp[8];
#pragma unroll
            for (int j = 0; j < 8; ++j)
                tmp[j] = f2bf(tile[kc + j][mr]);
            *reinterpret_cast<uint4*>(&Bt[(size_t)(m0 + mr) * MGRD + k0 + kc]) =
                *reinterpret_cast<const uint4*>(tmp);
        }
    }
}

// ---------------- R7: K-split-wave triangular GEMM ----------------
// 512 blocks of 256n x 128m, BK=64, 512 thr / 8 waves. Waves split by K-slice:
// kg = w>>2 owns k-slice [kg*32, kg*32+32) of every K-tile; (nq,mq)=wq gives a
// 128n x 64m output per wave (acc 8x4 frags, 128 VGPR). vs R6's 64x64 waves:
// B LDS reads halve (96 vs 128 b128/K-tile -> 1152 cyc < 1241 MFMA cyc ->
// MFMA-bound), 16 indep MFMA per phase, 2 phases + 4 barriers per K-tile
// (was 4 phases / 8 barriers / 8-MFMA phases).
// Triple-buffered LDS (144 KB, 1 block/CU): stage T+2 while computing T;
// steady-state s_waitcnt vmcnt(6) once per K-tile (never 0 in loop); load
// flight ~3 phases > HBM latency. Balance: 1 block/CU + longest-first ids
// (bm = id>>4) => hardware backfill pairs L=64-2bm with L=2+2bm' -> every CU
// ~66 K-tile units (dynamic form of the verified R4 complementary pairing).
// Staging map, XOR swizzle, read addressing, C/D layout byte-identical to the
// verified R5/R6 kernel (kg replaces the old s loop index). Cross-kg partial
// sums reduced once via LDS scratch in the epilogue (fp32 add).

#define FENCE() asm volatile("" ::: "memory")
static __device__ __forceinline__ void bar() {
    FENCE(); __builtin_amdgcn_s_barrier(); FENCE();
}

__global__ __launch_bounds__(512, 2) void gemm_kh_kernel(
    const u16* __restrict__ A,    // [4096][4096] bf16 (n-major, k contiguous)
    const u16* __restrict__ Bt,   // [4096][4096] bf16 (m-major, k contiguous)
    float* __restrict__ C)        // [4096][4096] fp32
{
    // 3 x (A 256x64 + B 128x64) bf16 = 3 x 48 KB = 144 KB (gfx950 LDS 160 KB)
    __shared__ u16 lds[3 * 24576] __attribute__((aligned(16)));

    const int tid  = threadIdx.x;
    const int lane = tid & 63;
    const int w    = tid >> 6;          // 0..7
    const int kg   = w >> 2;            // K-slice group: 0 -> k[0:32), 1 -> k[32:64)
    const int wq   = w & 3;
    const int nq   = wq >> 1;           // n-half: 128 rows
    const int mq   = wq & 1;            // m-half: 64 cols
    const int lrow = lane & 15;
    const int lhi  = lane >> 4;         // 0..3
    const int r7   = lrow & 7;

    const int id  = blockIdx.x;
    const int bm  = id >> 4;            // 0..31, longest (bm=0) first
    const int bn  = id & 15;
    const int bn0 = bn << 8;            // 256-row n tile
    const int bm0 = bm << 7;            // 128-row m tile
    const int L   = 64 - 2 * bm;        // K-tiles, even, >= 2

    // ---- staging source offsets (identical map to verified kernel) ----
    // inst r covers rows r*64 + (tid>>3); slot q=tid&7 holds global chunk
    // q ^ (row&7)  (== ((tid ^ (tid>>3)) & 7)).
    const int arow = tid >> 3;                       // 0..63
    const int aswz = ((tid ^ arow) & 7) * 8;
    int aoff[4], boff[2];
#pragma unroll
    for (int r = 0; r < 4; ++r)
        aoff[r] = (bn0 + r * 64 + arow) * 4096 + aswz;
#pragma unroll
    for (int r = 0; r < 2; ++r)
        boff[r] = (bm0 + r * 64 + arow) * 4096 + aswz;

    const int ldst = w * 512;                        // wave chunk (elems) within inst region
    // read-side: un-swizzled chunk (kg*4+lhi) ^ r7 (verified pattern, s := kg)
    const int cswz = ((kg * 4 + lhi) ^ r7) * 8;
    const int rowA = (nq * 128 + lrow) * 64 + cswz;
    const int rowB = (mq * 64  + lrow) * 64 + cswz;

#define STG_A(QA, R, K) __builtin_amdgcn_global_load_lds(                        \
    (const __attribute__((address_space(1))) void*)(A + (size_t)aoff[R] + (K)),  \
    (__attribute__((address_space(3))) void*)((QA) + (R) * 4096 + ldst), 16, 0, 0)
#define STG_B(QB, R, K) __builtin_amdgcn_global_load_lds(                        \
    (const __attribute__((address_space(1))) void*)(Bt + (size_t)boff[R] + (K)), \
    (__attribute__((address_space(3))) void*)((QB) + (R) * 4096 + ldst), 16, 0, 0)

    bf16x8 af[4], bfv[4];

#define RDA(PA, IB) do {                                                         \
    af[0] = *reinterpret_cast<const bf16x8*>((PA) + rowA + ((IB) + 0) * 1024);   \
    af[1] = *reinterpret_cast<const bf16x8*>((PA) + rowA + ((IB) + 1) * 1024);   \
    af[2] = *reinterpret_cast<const bf16x8*>((PA) + rowA + ((IB) + 2) * 1024);   \
    af[3] = *reinterpret_cast<const bf16x8*>((PA) + rowA + ((IB) + 3) * 1024);   \
} while (0)
#define RDB(PB) do {                                                             \
    bfv[0] = *reinterpret_cast<const bf16x8*>((PB) + rowB + 0 * 1024);           \
    bfv[1] = *reinterpret_cast<const bf16x8*>((PB) + rowB + 1 * 1024);           \
    bfv[2] = *reinterpret_cast<const bf16x8*>((PB) + rowB + 2 * 1024);           \
    bfv[3] = *reinterpret_cast<const bf16x8*>((PB) + rowB + 3 * 1024);           \
} while (0)

    floatx4 acc[8][4];
#pragma unroll
    for (int i = 0; i < 8; ++i)
#pragma unroll
        for (int j = 0; j < 4; ++j)
            acc[i][j] = (floatx4)0.0f;

#define MF(a, b, c) __builtin_amdgcn_mfma_f32_16x16x32_bf16(a, b, c, 0, 0, 0)
#define MFMA16(IB) do {                                                          \
    __builtin_amdgcn_s_setprio(1);                                               \
    acc[(IB)+0][0] = MF(af[0], bfv[0], acc[(IB)+0][0]);                          \
    acc[(IB)+0][1] = MF(af[0], bfv[1], acc[(IB)+0][1]);                          \
    acc[(IB)+0][2] = MF(af[0], bfv[2], acc[(IB)+0][2]);                          \
    acc[(IB)+0][3] = MF(af[0], bfv[3], acc[(IB)+0][3]);                          \
    acc[(IB)+1][0] = MF(af[1], bfv[0], acc[(IB)+1][0]);                          \
    acc[(IB)+1][1] = MF(af[1], bfv[1], acc[(IB)+1][1]);                          \
    acc[(IB)+1][2] = MF(af[1], bfv[2], acc[(IB)+1][2]);                          \
    acc[(IB)+1][3] = MF(af[1], bfv[3], acc[(IB)+1][3]);                          \
    acc[(IB)+2][0] = MF(af[2], bfv[0], acc[(IB)+2][0]);                          \
    acc[(IB)+2][1] = MF(af[2], bfv[1], acc[(IB)+2][1]);                          \
    acc[(IB)+2][2] = MF(af[2], bfv[2], acc[(IB)+2][2]);                          \
    acc[(IB)+2][3] = MF(af[2], bfv[3], acc[(IB)+2][3]);                          \
    acc[(IB)+3][0] = MF(af[3], bfv[0], acc[(IB)+3][0]);                          \
    acc[(IB)+3][1] = MF(af[3], bfv[1], acc[(IB)+3][1]);                          \
    acc[(IB)+3][2] = MF(af[3], bfv[2], acc[(IB)+3][2]);                          \
    acc[(IB)+3][3] = MF(af[3], bfv[3], acc[(IB)+3][3]);                          \
    __builtin_amdgcn_s_setprio(0);                                               \
} while (0)

    // ---- prologue: stage tiles 0 and 1 (reverse-K: tile T at 4096-64(T+1)) ----
    int kT = 4096 - 64;                 // k of tile currently computed
    {
        u16* qA0 = lds;                 u16* qB0 = lds + 16384;
        u16* qA1 = lds + 24576;         u16* qB1 = lds + 24576 + 16384;
        STG_A(qA0, 0, kT); STG_A(qA0, 1, kT); STG_A(qA0, 2, kT); STG_A(qA0, 3, kT);
        STG_B(qB0, 0, kT); STG_B(qB0, 1, kT);
        STG_A(qA1, 0, kT - 64); STG_A(qA1, 1, kT - 64);
        STG_A(qA1, 2, kT - 64); STG_A(qA1, 3, kT - 64);
        STG_B(qB1, 0, kT - 64); STG_B(qB1, 1, kT - 64);
    }
    asm volatile("s_waitcnt vmcnt(6)" ::: "memory");   // tile 0 arrived
    bar();

    // ---- main loop: compute T from buf p, stage T+2 into buf (p+2)%3 ----
    int p = 0;
    for (int T = 0; T < L - 2; ++T) {
        u16* pA = lds + p * 24576;      u16* pB = pA + 16384;
        int p2 = p + 2; if (p2 >= 3) p2 -= 3;
        u16* qA = lds + p2 * 24576;     u16* qB = qA + 16384;
        const int kst = kT - 128;       // k of tile T+2

        // Ph-a: frags i=0..3 + all B; issue half of T+2 staging
        RDA(pA, 0); RDB(pB);
        STG_A(qA, 0, kst); STG_A(qA, 1, kst); STG_B(qB, 0, kst);
        bar();
        MFMA16(0);
        bar();
        // Ph-b: frags i=4..7; rest of T+2 staging
        RDA(pA, 4);
        STG_A(qA, 2, kst); STG_A(qA, 3, kst); STG_B(qB, 1, kst);
        bar();
        MFMA16(4);
        asm volatile("s_waitcnt vmcnt(6)" ::: "memory");  // tile T+1 arrived
        bar();

        kT -= 64; ++p; if (p == 3) p = 0;
    }

    // ---- peel T = L-2 (no staging; drain for last tile) ----
    {
        u16* pA = lds + p * 24576;      u16* pB = pA + 16384;
        RDA(pA, 0); RDB(pB);
        bar();
        MFMA16(0);
        bar();
        RDA(pA, 4);
        bar();
        MFMA16(4);
        asm volatile("s_waitcnt vmcnt(0)" ::: "memory");  // tile L-1 arrived
        bar();
        kT -= 64; ++p; if (p == 3) p = 0;
    }
    // ---- peel T = L-1 ----
    {
        u16* pA = lds + p * 24576;      u16* pB = pA + 16384;
        RDA(pA, 0); RDB(pB);
        bar();
        MFMA16(0);
        bar();
        RDA(pA, 4);
        bar();
        MFMA16(4);
    }

    // ---- epilogue: cross-kg reduce via LDS scratch, then store ----
    __syncthreads();                    // all LDS reads done; reuse as fp32 scratch
    float* scr = reinterpret_cast<float*>(lds);   // 4 regions x 32 KB = 128 KB used
    if (kg == 1) {
#pragma unroll
        for (int i = 0; i < 8; ++i)
#pragma unroll
            for (int j = 0; j < 4; ++j)
                *reinterpret_cast<floatx4*>(
                    scr + (size_t)wq * 8192 + (i * 4 + j) * 256 + lane * 4) = acc[i][j];
    }
    __syncthreads();
    if (kg == 0) {
#pragma unroll
        for (int i = 0; i < 8; ++i)
#pragma unroll
            for (int j = 0; j < 4; ++j)
                acc[i][j] += *reinterpret_cast<const floatx4*>(
                    scr + (size_t)wq * 8192 + (i * 4 + j) * 256 + lane * 4);

        // C/D layout: col = lane&15 (m), row = (lane>>4)*4 + reg (n)  [m89]
#pragma unroll
        for (int i = 0; i < 8; ++i) {
            int rown = bn0 + nq * 128 + i * 16 + lhi * 4;
#pragma unroll
            for (int j = 0; j < 4; ++j) {
                int colm = bm0 + mq * 64 + j * 16 + lrow;
                float* cp = C + (size_t)rown * 4096 + colm;
#pragma unroll
                for (int rr = 0; rr < 4; ++rr)
                    cp[(size_t)rr * 4096] = acc[i][j][rr];
            }
        }
    }
}

extern "C" void kernel_launch(void* const* d_in, const int* in_sizes, int n_in,
                              void* d_out, int out_size, void* d_ws, size_t ws_size,
                              hipStream_t stream)
{
    const float* x    = (const float*)d_in[0];   // [4096,8]
    const float* grid = (const float*)d_in[1];   // [4096,8]
    const float* ci   = (const float*)d_in[2];   // [4096,4096]
    const float* ls   = (const float*)d_in[3];   // [8]
    float* out = (float*)d_out;                  // [4096,4096] fp32

    u16* wsA  = (u16*)d_ws;                            // k_star bf16, 33.5 MB
    u16* wsBt = (u16*)d_ws + (size_t)MGRD * MGRD;      // chol_inv^T bf16, 33.5 MB

    prep_kernel<<<dim3(512 + 64 * 64), 256, 0, stream>>>(x, grid, ls, ci, wsA, wsBt);
    gemm_kh_kernel<<<dim3(512), 512, 0, stream>>>(wsA, wsBt, out);
}

// Round 3
// 185.085 us; speedup vs baseline: 1.0860x; 1.0251x over previous
//
#include <hip/hip_runtime.h>
#include <cstdint>
#include <cstddef>

typedef unsigned short u16;
typedef __bf16 bf16x8 __attribute__((ext_vector_type(8)));
typedef float floatx4 __attribute__((ext_vector_type(4)));

#define NPTS 4096
#define MGRD 4096
#define DDIM 8

// round-to-nearest-even fp32 -> bf16
static __device__ __forceinline__ u16 f2bf(float f) {
    uint32_t u = __float_as_uint(f);
    u += 0x7fffu + ((u >> 16) & 1u);
    return (u16)(u >> 16);
}

// ---------------- Fused prep (unchanged, verified) ----------------
__global__ __launch_bounds__(256) void prep_kernel(
    const float* __restrict__ x, const float* __restrict__ g,
    const float* __restrict__ ls, const float* __restrict__ B,
    u16* __restrict__ A, u16* __restrict__ Bt)
{
    __shared__ float tile[64][65];
    const int bid = blockIdx.x;
    const int tid = threadIdx.x;

    if (bid < 512) {
        const int kb = bid & 1;
        const int n0 = (bid >> 1) * 16;
        const int k0 = kb * 2048 + tid * 8;

        float il[DDIM];
#pragma unroll
        for (int d = 0; d < DDIM; ++d) il[d] = 1.0f / ls[d];

        float4 g0[8], g1[8];
#pragma unroll
        for (int r = 0; r < 8; ++r) {
            g0[r] = *reinterpret_cast<const float4*>(g + (size_t)(k0 + r) * DDIM);
            g1[r] = *reinterpret_cast<const float4*>(g + (size_t)(k0 + r) * DDIM + 4);
        }

        for (int nn = 0; nn < 16; ++nn) {
            const int n = n0 + nn;
            const float4 x0 = *reinterpret_cast<const float4*>(x + (size_t)n * DDIM);
            const float4 x1 = *reinterpret_cast<const float4*>(x + (size_t)n * DDIM + 4);
            alignas(16) u16 res[8];
#pragma unroll
            for (int r = 0; r < 8; ++r) {
                float s = fabsf(x0.x - g0[r].x) * il[0] + fabsf(x0.y - g0[r].y) * il[1]
                        + fabsf(x0.z - g0[r].z) * il[2] + fabsf(x0.w - g0[r].w) * il[3]
                        + fabsf(x1.x - g1[r].x) * il[4] + fabsf(x1.y - g1[r].y) * il[5]
                        + fabsf(x1.z - g1[r].z) * il[6] + fabsf(x1.w - g1[r].w) * il[7];
                res[r] = f2bf(__expf(-s));
            }
            *reinterpret_cast<uint4*>(A + (size_t)n * MGRD + k0) =
                *reinterpret_cast<const uint4*>(res);
        }
    } else {
        const int id = bid - 512;
        const int bx = id & 63;
        const int by = id >> 6;
        if (by < (bx & ~1)) return;
        const int k0 = by * 64;
        const int m0 = bx * 64;

#pragma unroll
        for (int r = 0; r < 4; ++r) {
            int c   = r * 256 + tid;
            int row = c >> 4;
            int col = (c & 15) * 4;
            const float4 v = *reinterpret_cast<const float4*>(&B[(size_t)(k0 + row) * MGRD + m0 + col]);
            tile[row][col + 0] = v.x; tile[row][col + 1] = v.y;
            tile[row][col + 2] = v.z; tile[row][col + 3] = v.w;
        }
        __syncthreads();

#pragma unroll
        for (int r = 0; r < 2; ++r) {
            int c  = r * 256 + tid;
            int mr = c >> 3;
            int kc = (c & 7) * 8;
            alignas(16) u16 tmp[8];
#pragma unroll
            for (int j = 0; j < 8; ++j)
                tmp[j] = f2bf(tile[kc + j][mr]);
            *reinterpret_cast<uint4*>(&Bt[(size_t)(m0 + mr) * MGRD + k0 + kc]) =
                *reinterpret_cast<const uint4*>(tmp);
        }
    }
}

// ---------------- R8: single-barrier-per-K-tile triangular GEMM ----------------
// R6/R7 post-mortem: every phase-lockstep schedule lands at ~3065 cyc/K-tile =
// LDS reads (1152) + MFMA (1241) + stage-writes (~380) SUMMED -- the per-phase
// [reads][barrier][lgkm][MFMA][barrier] structure lets the LDS pipe and the
// matrix pipe strictly alternate, never overlap. Fix: ONE barrier per K-tile.
// Per tile each wave: issue 6 stage loads (tile T+2) -> issue all 12 ds_reads
// into 12 DISTINCT regs (af[8], bfv[4]; no WAR reuse) -> 32 MFMAs under
// compiler fine-grained lgkmcnt (read order af0,b0..b3,af1..af7: first MFMA
// needs only 5 reads) -> vmcnt(6) -> barrier. LDS pipe now drains reads while
// the matrix pipe runs; per-tile target ~1500-1700 cyc.
// Decomposition (unchanged, verified R7): 512 blocks of 256n x 128m, 8 waves =
// 2kg x 2nq x 2mq, per-wave 128n x 64m at one 32-wide K-slice. Triple-buffered
// LDS 144 KB, stage T+2 while computing T; vmcnt(6) once per tile (never 0 in
// loop). Ledger: stage at T targets buf (T+2)%3 == (T-1)%3, whose reads were
// drained by T-1's MFMAs before the T-1 barrier (all waves) -- safe.
// Longest-first ids (bm = id>>4) + 1 block/CU => backfill pairs L=64-2bm with
// complementary L => every CU ~66 K-tile units. Staging map, XOR swizzle,
// read addressing, C/D layout, epilogue reduce byte-identical to verified R7.

#define FENCE() asm volatile("" ::: "memory")
static __device__ __forceinline__ void bar() {
    FENCE(); __builtin_amdgcn_s_barrier(); FENCE();
}

__global__ __launch_bounds__(512, 2) void gemm_sb_kernel(
    const u16* __restrict__ A,    // [4096][4096] bf16 (n-major, k contiguous)
    const u16* __restrict__ Bt,   // [4096][4096] bf16 (m-major, k contiguous)
    float* __restrict__ C)        // [4096][4096] fp32
{
    // 3 x (A 256x64 + B 128x64) bf16 = 3 x 48 KB = 144 KB
    __shared__ u16 lds[3 * 24576] __attribute__((aligned(16)));

    const int tid  = threadIdx.x;
    const int lane = tid & 63;
    const int w    = tid >> 6;          // 0..7
    const int kg   = w >> 2;            // K-slice group: 0 -> k[0:32), 1 -> k[32:64)
    const int wq   = w & 3;
    const int nq   = wq >> 1;           // n-half: 128 rows
    const int mq   = wq & 1;            // m-half: 64 cols
    const int lrow = lane & 15;
    const int lhi  = lane >> 4;         // 0..3
    const int r7   = lrow & 7;

    const int id  = blockIdx.x;
    const int bm  = id >> 4;            // 0..31, longest (bm=0) first
    const int bn  = id & 15;
    const int bn0 = bn << 8;            // 256-row n tile
    const int bm0 = bm << 7;            // 128-row m tile
    const int L   = 64 - 2 * bm;        // K-tiles, even, >= 2

    // ---- staging source offsets (verified map): inst r covers rows r*64+(tid>>3);
    // slot q=tid&7 holds global chunk q ^ (row&7).
    const int arow = tid >> 3;                       // 0..63
    const int aswz = ((tid ^ arow) & 7) * 8;
    int aoff[4], boff[2];
#pragma unroll
    for (int r = 0; r < 4; ++r)
        aoff[r] = (bn0 + r * 64 + arow) * 4096 + aswz;
#pragma unroll
    for (int r = 0; r < 2; ++r)
        boff[r] = (bm0 + r * 64 + arow) * 4096 + aswz;

    const int ldst = w * 512;           // wave chunk (elems) within inst region
    // read-side: un-swizzled chunk (kg*4+lhi) ^ r7 (verified pattern)
    const int cswz = ((kg * 4 + lhi) ^ r7) * 8;
    const int rowA = (nq * 128 + lrow) * 64 + cswz;
    const int rowB = (mq * 64  + lrow) * 64 + cswz;

#define STG_A(QA, R, K) __builtin_amdgcn_global_load_lds(                        \
    (const __attribute__((address_space(1))) void*)(A + (size_t)aoff[R] + (K)),  \
    (__attribute__((address_space(3))) void*)((QA) + (R) * 4096 + ldst), 16, 0, 0)
#define STG_B(QB, R, K) __builtin_amdgcn_global_load_lds(                        \
    (const __attribute__((address_space(1))) void*)(Bt + (size_t)boff[R] + (K)), \
    (__attribute__((address_space(3))) void*)((QB) + (R) * 4096 + ldst), 16, 0, 0)

    bf16x8 af[8], bfv[4];

    // read order: first MFMA (af[0] x bfv[0]) ready after 5 reads
#define RDALL(PA, PB) do {                                                       \
    af[0]  = *reinterpret_cast<const bf16x8*>((PA) + rowA + 0 * 1024);           \
    bfv[0] = *reinterpret_cast<const bf16x8*>((PB) + rowB + 0 * 1024);           \
    bfv[1] = *reinterpret_cast<const bf16x8*>((PB) + rowB + 1 * 1024);           \
    bfv[2] = *reinterpret_cast<const bf16x8*>((PB) + rowB + 2 * 1024);           \
    bfv[3] = *reinterpret_cast<const bf16x8*>((PB) + rowB + 3 * 1024);           \
    af[1]  = *reinterpret_cast<const bf16x8*>((PA) + rowA + 1 * 1024);           \
    af[2]  = *reinterpret_cast<const bf16x8*>((PA) + rowA + 2 * 1024);           \
    af[3]  = *reinterpret_cast<const bf16x8*>((PA) + rowA + 3 * 1024);           \
    af[4]  = *reinterpret_cast<const bf16x8*>((PA) + rowA + 4 * 1024);           \
    af[5]  = *reinterpret_cast<const bf16x8*>((PA) + rowA + 5 * 1024);           \
    af[6]  = *reinterpret_cast<const bf16x8*>((PA) + rowA + 6 * 1024);           \
    af[7]  = *reinterpret_cast<const bf16x8*>((PA) + rowA + 7 * 1024);           \
} while (0)

    floatx4 acc[8][4];
#pragma unroll
    for (int i = 0; i < 8; ++i)
#pragma unroll
        for (int j = 0; j < 4; ++j)
            acc[i][j] = (floatx4)0.0f;

#define MF(a, b, c) __builtin_amdgcn_mfma_f32_16x16x32_bf16(a, b, c, 0, 0, 0)
#define MFMA32() do {                                                            \
    __builtin_amdgcn_s_setprio(1);                                               \
    _Pragma("unroll")                                                            \
    for (int i_ = 0; i_ < 8; ++i_)                                               \
        _Pragma("unroll")                                                        \
        for (int j_ = 0; j_ < 4; ++j_)                                           \
            acc[i_][j_] = MF(af[i_], bfv[j_], acc[i_][j_]);                      \
    __builtin_amdgcn_s_setprio(0);                                               \
} while (0)

    // ---- prologue: stage tiles 0 and 1 (reverse-K: tile T at k = 4032 - 64T) ----
    int kT = 4096 - 64;                 // k of tile currently computed
    {
        u16* qA0 = lds;                 u16* qB0 = lds + 16384;
        u16* qA1 = lds + 24576;         u16* qB1 = lds + 24576 + 16384;
        STG_A(qA0, 0, kT); STG_A(qA0, 1, kT); STG_A(qA0, 2, kT); STG_A(qA0, 3, kT);
        STG_B(qB0, 0, kT); STG_B(qB0, 1, kT);
        STG_A(qA1, 0, kT - 64); STG_A(qA1, 1, kT - 64);
        STG_A(qA1, 2, kT - 64); STG_A(qA1, 3, kT - 64);
        STG_B(qB1, 0, kT - 64); STG_B(qB1, 1, kT - 64);
    }
    asm volatile("s_waitcnt vmcnt(6)" ::: "memory");   // tile 0 arrived
    bar();

    // ---- main loop: single region per K-tile, one barrier ----
    int p = 0;
    for (int T = 0; T < L - 2; ++T) {
        u16* pA = lds + p * 24576;      u16* pB = pA + 16384;
        int p2 = p + 2; if (p2 >= 3) p2 -= 3;
        u16* qA = lds + p2 * 24576;     u16* qB = qA + 16384;
        const int kst = kT - 128;       // k of tile T+2

        STG_A(qA, 0, kst); STG_A(qA, 1, kst); STG_A(qA, 2, kst); STG_A(qA, 3, kst);
        STG_B(qB, 0, kst); STG_B(qB, 1, kst);
        RDALL(pA, pB);
        MFMA32();
        asm volatile("s_waitcnt vmcnt(6)" ::: "memory");  // tile T+1 arrived
        bar();

        kT -= 64; ++p; if (p == 3) p = 0;
    }

    // ---- peel T = L-2 (no staging; drain last tile) ----
    {
        u16* pA = lds + p * 24576;      u16* pB = pA + 16384;
        RDALL(pA, pB);
        MFMA32();
        asm volatile("s_waitcnt vmcnt(0)" ::: "memory");  // tile L-1 arrived
        bar();
        ++p; if (p == 3) p = 0;
    }
    // ---- peel T = L-1 ----
    {
        u16* pA = lds + p * 24576;      u16* pB = pA + 16384;
        RDALL(pA, pB);
        MFMA32();
    }

    // ---- epilogue: cross-kg reduce via LDS scratch, then store (verified) ----
    __syncthreads();                    // all LDS reads done; reuse as fp32 scratch
    float* scr = reinterpret_cast<float*>(lds);   // 4 regions x 32 KB = 128 KB used
    if (kg == 1) {
#pragma unroll
        for (int i = 0; i < 8; ++i)
#pragma unroll
            for (int j = 0; j < 4; ++j)
                *reinterpret_cast<floatx4*>(
                    scr + (size_t)wq * 8192 + (i * 4 + j) * 256 + lane * 4) = acc[i][j];
    }
    __syncthreads();
    if (kg == 0) {
#pragma unroll
        for (int i = 0; i < 8; ++i)
#pragma unroll
            for (int j = 0; j < 4; ++j)
                acc[i][j] += *reinterpret_cast<const floatx4*>(
                    scr + (size_t)wq * 8192 + (i * 4 + j) * 256 + lane * 4);

        // C/D layout: col = lane&15 (m), row = (lane>>4)*4 + reg (n)  [m89]
#pragma unroll
        for (int i = 0; i < 8; ++i) {
            int rown = bn0 + nq * 128 + i * 16 + lhi * 4;
#pragma unroll
            for (int j = 0; j < 4; ++j) {
                int colm = bm0 + mq * 64 + j * 16 + lrow;
                float* cp = C + (size_t)rown * 4096 + colm;
#pragma unroll
                for (int rr = 0; rr < 4; ++rr)
                    cp[(size_t)rr * 4096] = acc[i][j][rr];
            }
        }
    }
}

extern "C" void kernel_launch(void* const* d_in, const int* in_sizes, int n_in,
                              void* d_out, int out_size, void* d_ws, size_t ws_size,
                              hipStream_t stream)
{
    const float* x    = (const float*)d_in[0];   // [4096,8]
    const float* grid = (const float*)d_in[1];   // [4096,8]
    const float* ci   = (const float*)d_in[2];   // [4096,4096]
    const float* ls   = (const float*)d_in[3];   // [8]
    float* out = (float*)d_out;                  // [4096,4096] fp32

    u16* wsA  = (u16*)d_ws;                            // k_star bf16, 33.5 MB
    u16* wsBt = (u16*)d_ws + (size_t)MGRD * MGRD;      // chol_inv^T bf16, 33.5 MB

    prep_kernel<<<dim3(512 + 64 * 64), 256, 0, stream>>>(x, grid, ls, ci, wsA, wsBt);
    gemm_sb_kernel<<<dim3(512), 512, 0, stream>>>(wsA, wsBt, out);
}